// Round 1
// baseline (419.483 us; speedup 1.0000x reference)
//
#include <hip/hip_runtime.h>
#include <hip/hip_bf16.h>
#include <math.h>

typedef __attribute__((ext_vector_type(8))) short short8;
typedef __attribute__((ext_vector_type(4))) float f32x4;

#define DEVINL static __device__ __forceinline__

// ---------- constants ----------
// model dims
// B=4096, NE=64, DE=96, NA=8, NACT=16, DH=256, NH=4, HD=64, OD=64
static constexpr int NBPB = 2;            // batch items per block
static constexpr int NBLK = 4096 / NBPB;  // 2048 blocks

// weight-fragment offsets in d_ws (bf16 elements); layout [nt][kt][lane][8]
static constexpr int WE_OFF  = 0;       // K=96  N=256 (nkt=3)  -> 24576
static constexpr int WQ_OFF  = 24576;   // K=256 N=256 (nkt=8)  -> 65536
static constexpr int WK_OFF  = 90112;
static constexpr int WV_OFF  = 155648;
static constexpr int WO_OFF  = 221184;
static constexpr int WM1_OFF = 286720;
static constexpr int WM2_OFF = 352256;  // K=256 N=64 -> 16384
static constexpr int WL1_OFF = 368640;
static constexpr int WL2_OFF = 434176;  // total 450560 bf16 = 901120 B

// LDS byte offsets (dynamic shared). Regions are time-shared between phases.
static constexpr int XOFF    = 0;       // X  [2][64][256] bf16 swz, stride 512 (65536)
static constexpr int KOFF    = 65536;   // K  [2][64][256]  (phase 3-4)
static constexpr int VOFF    = 65536;   // Vt [2][256][64] stride 128 (phase 5-6)
static constexpr int HID_OFF = 65536;   // hidden [2][16][256] (phase 7-8)
static constexpr int M1_OFF  = 81920;   // m1 [2][16][256]
static constexpr int L1_OFF  = 98304;   // l1 [2][16][256]
static constexpr int QOFF    = 131072;  // q then attn [2][16][256] (16384)
static constexpr int WOFF2   = 147456;  // softmax w [2][4][8][64] stride 128 (8192)
static constexpr int EOFF    = 131072;  // E overlay [2][64][96] stride 192 (24576), dead before q written
static constexpr int ACT_OFF = 155648;  // 16 ints
static constexpr int LDS_BYTES = 155712;

DEVINL unsigned short f2bf(float f) {
  union { float f; unsigned u; } x; x.f = f;
  unsigned r = x.u + 0x7fffu + ((x.u >> 16) & 1u);
  return (unsigned short)(r >> 16);
}

DEVINL f32x4 mfma(short8 a, short8 b, f32x4 c) {
  return __builtin_amdgcn_mfma_f32_16x16x32_bf16(a, b, c, 0, 0, 0);
}

// B-fragment load from prepped weights: one coalesced 16B load per lane
DEVINL short8 ldfrag(const unsigned short* wf, int off, int nt, int kt, int nkt, int lane) {
  return *(const short8*)(wf + off + ((nt * nkt + kt) << 9) + (lane << 3));
}

// LDS 16B A/B-style fragment read from a stride-512B swizzled buffer
DEVINL short8 lda512(const char* sm, int base, int row, int colbyte) {
  return *(const short8*)(sm + base + row * 512 + (colbyte ^ ((row & 7) << 4)));
}

DEVINL void stb512(char* sm, int base, int row, int col, float v) {
  *(unsigned short*)(sm + base + row * 512 + ((col * 2) ^ ((row & 7) << 4))) = f2bf(v);
}

// ---------- prep kernel: fp32 weights -> bf16 MFMA B-fragments ----------
__global__ __launch_bounds__(512) void prep_kernel(
    const float* We, const float* Win, const float* Wout, const float* Wm1,
    const float* Wm2, const float* Wl1, const float* Wl2, unsigned short* wf) {
  const int m = blockIdx.y;
  const int Ks[9]   = {96, 256, 256, 256, 256, 256, 256, 256, 256};
  const int Ns[9]   = {256, 256, 256, 256, 256, 256, 64, 256, 64};
  const int lds_[9] = {256, 768, 768, 768, 256, 256, 64, 256, 64};
  const int coff[9] = {0, 0, 256, 512, 0, 0, 0, 0, 0};
  const int dsto[9] = {WE_OFF, WQ_OFF, WK_OFF, WV_OFF, WO_OFF, WM1_OFF, WM2_OFF, WL1_OFF, WL2_OFF};
  const float* srcs[9] = {We, Win, Win, Win, Wout, Wm1, Wm2, Wl1, Wl2};
  const int K = Ks[m], N = Ns[m], nkt = K / 32;
  const int total = (N / 16) * nkt * 512;
  const int idx = blockIdx.x * 512 + threadIdx.x;
  if (idx >= total) return;
  const int j = idx & 7, lane = (idx >> 3) & 63;
  const int kt = (idx >> 9) % nkt, nt = idx / (512 * nkt);
  const int row = kt * 32 + ((lane >> 4) << 3) + j;   // K index
  const int col = nt * 16 + (lane & 15);              // N index
  wf[dsto[m] + idx] = f2bf(srcs[m][(long)row * lds_[m] + coff[m] + col]);
}

// ---------- fused main kernel: 1 block = 2 batch items ----------
__global__ __launch_bounds__(512, 2) void fused_kernel(
    const float* __restrict__ entities, const int* __restrict__ entity_mask,
    const int* __restrict__ obs_mask, const float* __restrict__ acts,
    const float* __restrict__ Wa, const float* __restrict__ be,
    const float* __restrict__ bout, const float* __restrict__ bm1,
    const float* __restrict__ bm2, const float* __restrict__ bl1,
    const float* __restrict__ bl2, const unsigned short* __restrict__ wf,
    float* __restrict__ out) {
  extern __shared__ char sm[];
  const int tid = threadIdx.x;
  const int w = tid >> 6, lane = tid & 63;
  const int g = lane >> 4, c = lane & 15;
  const int ig0 = blockIdx.x * 2;
  const int nt0 = w * 2;  // N-tile pair owned by this wave in N-split phases

  // ---- phase 0: entities -> bf16 LDS (swizzled), action ids
  {
    const int it = tid >> 8, i = tid & 255;
    const int row = i >> 2, q4 = i & 3;
    const float* src = entities + (long)(ig0 + it) * 6144 + row * 96 + q4 * 24;
    const int ebase = EOFF + it * 12288 + row * 192;
    const int sw = (row & 3) << 4;
#pragma unroll
    for (int ch = 0; ch < 3; ++ch) {
      short8 s;
#pragma unroll
      for (int k = 0; k < 8; ++k) s[k] = (short)f2bf(src[ch * 8 + k]);
      *(short8*)(sm + ebase + ((q4 * 48 + ch * 16) ^ sw)) = s;
    }
    if (tid < 16) {
      const float* oh = acts + ((long)(ig0 + (tid >> 3)) * 8 + (tid & 7)) * 16;
      int id = 0;
      for (int a = 0; a < 16; ++a) if (oh[a] > 0.5f) id = a;
      ((int*)(sm + ACT_OFF))[tid] = id;
    }
  }
  __syncthreads();

  // ---- phase 1: he = E @ We + be (+ha rows<8), relu -> X
  {
    f32x4 acc[2][4][2] = {};
#pragma unroll
    for (int kt = 0; kt < 3; ++kt) {
      short8 b0 = ldfrag(wf, WE_OFF, nt0, kt, 3, lane);
      short8 b1 = ldfrag(wf, WE_OFF, nt0 + 1, kt, 3, lane);
#pragma unroll
      for (int it = 0; it < 2; ++it)
#pragma unroll
        for (int mt = 0; mt < 4; ++mt) {
          const int row = mt * 16 + c;
          short8 a = *(const short8*)(sm + EOFF + it * 12288 + row * 192 +
                                      ((kt * 64 + (g << 4)) ^ ((row & 3) << 4)));
          acc[it][mt][0] = mfma(a, b0, acc[it][mt][0]);
          acc[it][mt][1] = mfma(a, b1, acc[it][mt][1]);
        }
    }
    float bev[2] = {be[nt0 * 16 + c], be[nt0 * 16 + 16 + c]};
#pragma unroll
    for (int it = 0; it < 2; ++it)
#pragma unroll
      for (int mt = 0; mt < 4; ++mt)
#pragma unroll
        for (int n = 0; n < 2; ++n)
#pragma unroll
          for (int r = 0; r < 4; ++r) {
            const int row = mt * 16 + g * 4 + r;
            const int col = (nt0 + n) * 16 + c;
            float v = acc[it][mt][n][r] + bev[n];
            if (row < 8) {
              int id = ((const int*)(sm + ACT_OFF))[it * 8 + row];
              v += Wa[id * 256 + col];
            }
            v = fmaxf(v, 0.f);
            stb512(sm, XOFF + it * 32768, row, col, v);
          }
  }
  __syncthreads();

  // ---- phase 2: q = X[0:16] @ Wq -> q_lds (overlays dead E region)
  {
    f32x4 qa[2][2] = {};
#pragma unroll
    for (int kt = 0; kt < 8; ++kt) {
      short8 b0 = ldfrag(wf, WQ_OFF, nt0, kt, 8, lane);
      short8 b1 = ldfrag(wf, WQ_OFF, nt0 + 1, kt, 8, lane);
#pragma unroll
      for (int it = 0; it < 2; ++it) {
        short8 a = lda512(sm, XOFF + it * 32768, c, kt * 64 + (g << 4));
        qa[it][0] = mfma(a, b0, qa[it][0]);
        qa[it][1] = mfma(a, b1, qa[it][1]);
      }
    }
#pragma unroll
    for (int it = 0; it < 2; ++it)
#pragma unroll
      for (int n = 0; n < 2; ++n)
#pragma unroll
        for (int r = 0; r < 4; ++r)
          stb512(sm, QOFF + it * 8192, g * 4 + r, (nt0 + n) * 16 + c, qa[it][n][r]);
  }
  __syncthreads();

  // ---- phase 3: k = X @ Wk -> K_lds
  {
    f32x4 acc[2][4][2] = {};
#pragma unroll
    for (int kt = 0; kt < 8; ++kt) {
      short8 b0 = ldfrag(wf, WK_OFF, nt0, kt, 8, lane);
      short8 b1 = ldfrag(wf, WK_OFF, nt0 + 1, kt, 8, lane);
#pragma unroll
      for (int it = 0; it < 2; ++it)
#pragma unroll
        for (int mt = 0; mt < 4; ++mt) {
          short8 a = lda512(sm, XOFF + it * 32768, mt * 16 + c, kt * 64 + (g << 4));
          acc[it][mt][0] = mfma(a, b0, acc[it][mt][0]);
          acc[it][mt][1] = mfma(a, b1, acc[it][mt][1]);
        }
    }
#pragma unroll
    for (int it = 0; it < 2; ++it)
#pragma unroll
      for (int mt = 0; mt < 4; ++mt)
#pragma unroll
        for (int n = 0; n < 2; ++n)
#pragma unroll
          for (int r = 0; r < 4; ++r)
            stb512(sm, KOFF + it * 32768, mt * 16 + g * 4 + r, (nt0 + n) * 16 + c,
                   acc[it][mt][n][r]);
  }
  __syncthreads();

  // ---- phase 4: logits = q @ k^T (per head), mask, softmax -> w_lds
  {
    const int it = w >> 2, h = w & 3;
    const long ig = ig0 + it;
    f32x4 lac[4] = {};
#pragma unroll
    for (int kt = 0; kt < 2; ++kt) {
      const int colb = h * 128 + kt * 64 + (g << 4);
      short8 aq = lda512(sm, QOFF + it * 8192, c, colb);
#pragma unroll
      for (int nt = 0; nt < 4; ++nt) {
        short8 bk = lda512(sm, KOFF + it * 32768, nt * 16 + c, colb);
        lac[nt] = mfma(aq, bk, lac[nt]);
      }
    }
    const int* obs = obs_mask + ig * 4096;
#pragma unroll
    for (int r = 0; r < 4; ++r) {
      const int qi = g * 4 + r;
      float vals[4];
#pragma unroll
      for (int nt = 0; nt < 4; ++nt) {
        int msk = obs[qi * 64 + nt * 16 + c];
        vals[nt] = msk ? -INFINITY : lac[nt][r] * 0.125f;
      }
      float mx = fmaxf(fmaxf(vals[0], vals[1]), fmaxf(vals[2], vals[3]));
#pragma unroll
      for (int d = 1; d < 16; d <<= 1) mx = fmaxf(mx, __shfl_xor(mx, d, 64));
      float s = 0.f;
#pragma unroll
      for (int nt = 0; nt < 4; ++nt) {
        float e = (mx == -INFINITY) ? 0.f : expf(vals[nt] - mx);
        vals[nt] = e; s += e;
      }
#pragma unroll
      for (int d = 1; d < 16; d <<= 1) s += __shfl_xor(s, d, 64);
      const float inv = (s > 0.f) ? 1.f / s : 0.f;
      if (qi < 8) {
#pragma unroll
        for (int nt = 0; nt < 4; ++nt) {
          const int key = nt * 16 + c;
          *(unsigned short*)(sm + WOFF2 + ((it * 4 + h) * 8 + qi) * 128 +
                             ((key * 2) ^ (qi << 4))) = f2bf(vals[nt] * inv);
        }
      }
    }
  }
  __syncthreads();

  // ---- phase 5: v = X @ Wv -> Vt (transposed, overwrites K region)
  {
    f32x4 acc[2][4][2] = {};
#pragma unroll
    for (int kt = 0; kt < 8; ++kt) {
      short8 b0 = ldfrag(wf, WV_OFF, nt0, kt, 8, lane);
      short8 b1 = ldfrag(wf, WV_OFF, nt0 + 1, kt, 8, lane);
#pragma unroll
      for (int it = 0; it < 2; ++it)
#pragma unroll
        for (int mt = 0; mt < 4; ++mt) {
          short8 a = lda512(sm, XOFF + it * 32768, mt * 16 + c, kt * 64 + (g << 4));
          acc[it][mt][0] = mfma(a, b0, acc[it][mt][0]);
          acc[it][mt][1] = mfma(a, b1, acc[it][mt][1]);
        }
    }
#pragma unroll
    for (int it = 0; it < 2; ++it)
#pragma unroll
      for (int mt = 0; mt < 4; ++mt)
#pragma unroll
        for (int n = 0; n < 2; ++n) {
          const int d = (nt0 + n) * 16 + c;
          const int key0 = mt * 16 + g * 4;
          unsigned long long pk = 0;
#pragma unroll
          for (int r = 0; r < 4; ++r)
            pk |= (unsigned long long)f2bf(acc[it][mt][n][r]) << (16 * r);
          *(unsigned long long*)(sm + VOFF + it * 32768 + d * 128 +
                                 ((key0 * 2) ^ ((d & 7) << 4))) = pk;
        }
  }
  __syncthreads();

  // ---- phase 6: attn = w @ v (per head) -> attn_lds (overlays dead q region)
  {
    const int it = w >> 2, h = w & 3;
    f32x4 aac[4] = {};
#pragma unroll
    for (int kt = 0; kt < 2; ++kt) {
      const int kb = kt * 64 + (g << 4);  // 2*(kt*32+g*8)
      const int wrow = c & 7;             // clamp: rows 8-15 duplicate 0-7 (outputs unused)
      short8 aw = *(const short8*)(sm + WOFF2 + ((it * 4 + h) * 8 + wrow) * 128 +
                                   (kb ^ (wrow << 4)));
#pragma unroll
      for (int n = 0; n < 4; ++n) {
        const int d = (h * 4 + n) * 16 + c;
        short8 bv = *(const short8*)(sm + VOFF + it * 32768 + d * 128 +
                                     (kb ^ ((d & 7) << 4)));
        aac[n] = mfma(aw, bv, aac[n]);
      }
    }
#pragma unroll
    for (int n = 0; n < 4; ++n)
#pragma unroll
      for (int r = 0; r < 4; ++r)
        stb512(sm, QOFF + it * 8192, g * 4 + r, (h * 4 + n) * 16 + c, aac[n][r]);
  }
  __syncthreads();

  // ---- phase 7: hidden = mask/relu(attn @ Wout + bout) -> hidden_lds
  {
    f32x4 acc[2][2] = {};
#pragma unroll
    for (int kt = 0; kt < 8; ++kt) {
      short8 b0 = ldfrag(wf, WO_OFF, nt0, kt, 8, lane);
      short8 b1 = ldfrag(wf, WO_OFF, nt0 + 1, kt, 8, lane);
#pragma unroll
      for (int it = 0; it < 2; ++it) {
        short8 a = lda512(sm, QOFF + it * 8192, c, kt * 64 + (g << 4));
        acc[it][0] = mfma(a, b0, acc[it][0]);
        acc[it][1] = mfma(a, b1, acc[it][1]);
      }
    }
    float bo[2] = {bout[nt0 * 16 + c], bout[nt0 * 16 + 16 + c]};
#pragma unroll
    for (int it = 0; it < 2; ++it) {
      const int* em = entity_mask + (long)(ig0 + it) * 64;
#pragma unroll
      for (int n = 0; n < 2; ++n)
#pragma unroll
        for (int r = 0; r < 4; ++r) {
          const int row = g * 4 + r;
          float v = acc[it][n][r] + bo[n];
          v = em[row] ? 0.f : fmaxf(v, 0.f);
          stb512(sm, HID_OFF + it * 8192, row, (nt0 + n) * 16 + c, v);
        }
    }
  }
  __syncthreads();

  // ---- phase 8: m1 = relu(hidden@Wm1+bm1), l1 = relu(hidden@Wl1+bl1)
  {
    f32x4 am[2][2] = {}, al[2][2] = {};
#pragma unroll
    for (int kt = 0; kt < 8; ++kt) {
      short8 bm0 = ldfrag(wf, WM1_OFF, nt0, kt, 8, lane);
      short8 bm1f = ldfrag(wf, WM1_OFF, nt0 + 1, kt, 8, lane);
      short8 bl0 = ldfrag(wf, WL1_OFF, nt0, kt, 8, lane);
      short8 bl1f = ldfrag(wf, WL1_OFF, nt0 + 1, kt, 8, lane);
#pragma unroll
      for (int it = 0; it < 2; ++it) {
        short8 a = lda512(sm, HID_OFF + it * 8192, c, kt * 64 + (g << 4));
        am[it][0] = mfma(a, bm0, am[it][0]);
        am[it][1] = mfma(a, bm1f, am[it][1]);
        al[it][0] = mfma(a, bl0, al[it][0]);
        al[it][1] = mfma(a, bl1f, al[it][1]);
      }
    }
    float bmv[2] = {bm1[nt0 * 16 + c], bm1[nt0 * 16 + 16 + c]};
    float blv[2] = {bl1[nt0 * 16 + c], bl1[nt0 * 16 + 16 + c]};
#pragma unroll
    for (int it = 0; it < 2; ++it)
#pragma unroll
      for (int n = 0; n < 2; ++n)
#pragma unroll
        for (int r = 0; r < 4; ++r) {
          const int row = g * 4 + r, col = (nt0 + n) * 16 + c;
          stb512(sm, M1_OFF + it * 8192, row, col, fmaxf(am[it][n][r] + bmv[n], 0.f));
          stb512(sm, L1_OFF + it * 8192, row, col, fmaxf(al[it][n][r] + blv[n], 0.f));
        }
  }
  __syncthreads();

  // ---- phase 9: mean = m1@Wm2+bm2 ; logvar = clip(l1@Wl2+bl2,-10,0) -> out
  {
    const int isv = (w >= 4);
    const int nt = w & 3;
    const int SRC = (isv ? L1_OFF : M1_OFF);
    const int WOF = (isv ? WL2_OFF : WM2_OFF);
    const float* bias = isv ? bl2 : bm2;
    f32x4 acc[2] = {};
#pragma unroll
    for (int kt = 0; kt < 8; ++kt) {
      short8 b = ldfrag(wf, WOF, nt, kt, 8, lane);
#pragma unroll
      for (int it = 0; it < 2; ++it) {
        short8 a = lda512(sm, SRC + it * 8192, c, kt * 64 + (g << 4));
        acc[it] = mfma(a, b, acc[it]);
      }
    }
    const float bv = bias[nt * 16 + c];
    const long obase = isv ? 2097152L : 0L;
#pragma unroll
    for (int it = 0; it < 2; ++it)
#pragma unroll
      for (int r = 0; r < 4; ++r) {
        const int qi = g * 4 + r;
        if (qi < 8) {
          float v = acc[it][r] + bv;
          if (isv) v = fminf(fmaxf(v, -10.f), 0.f);
          out[obase + (long)(ig0 + it) * 512 + qi * 64 + nt * 16 + c] = v;
        }
      }
  }
}

extern "C" void kernel_launch(void* const* d_in, const int* in_sizes, int n_in,
                              void* d_out, int out_size, void* d_ws, size_t ws_size,
                              hipStream_t stream) {
  const float* entities   = (const float*)d_in[0];
  const int*   entity_mask= (const int*)d_in[1];
  const int*   obs_mask   = (const int*)d_in[2];
  const float* acts       = (const float*)d_in[3];
  const float* We   = (const float*)d_in[4];
  const float* be   = (const float*)d_in[5];
  const float* Wa   = (const float*)d_in[6];
  const float* Win  = (const float*)d_in[7];
  const float* Wout = (const float*)d_in[8];
  const float* bout = (const float*)d_in[9];
  const float* Wm1  = (const float*)d_in[10];
  const float* bm1  = (const float*)d_in[11];
  const float* Wm2  = (const float*)d_in[12];
  const float* bm2  = (const float*)d_in[13];
  const float* Wl1  = (const float*)d_in[14];
  const float* bl1  = (const float*)d_in[15];
  const float* Wl2  = (const float*)d_in[16];
  const float* bl2  = (const float*)d_in[17];
  unsigned short* wf = (unsigned short*)d_ws;

  prep_kernel<<<dim3(128, 9), 512, 0, stream>>>(We, Win, Wout, Wm1, Wm2, Wl1, Wl2, wf);

  hipFuncSetAttribute((const void*)fused_kernel,
                      hipFuncAttributeMaxDynamicSharedMemorySize, LDS_BYTES);
  fused_kernel<<<NBLK, 512, LDS_BYTES, stream>>>(
      entities, entity_mask, obs_mask, acts, Wa, be, bout, bm1, bm2, bl1, bl2,
      wf, (float*)d_out);
}

// Round 2
// 352.624 us; speedup vs baseline: 1.1896x; 1.1896x over previous
//
#include <hip/hip_runtime.h>
#include <hip/hip_bf16.h>
#include <math.h>

typedef __attribute__((ext_vector_type(8))) short short8;
typedef __attribute__((ext_vector_type(4))) float f32x4;
typedef __attribute__((ext_vector_type(2))) unsigned int uint2v;

#define DEVINL static __device__ __forceinline__

// B=4096, NE=64, DE=96, NA=8, NACT=16, DH=256, NH=4, HD=64, OD=64
static constexpr int NBLK = 2048;   // 2 batch items per block

// weight-fragment offsets in d_ws (bf16 elements)
static constexpr int WE_OFF  = 0;        // K=96  N=256
static constexpr int WQ_OFF  = 24576;    // K=256 N=256
static constexpr int WKT_OFF = 90112;    // per-head Wk^T: 4h x 16dt x 2kt
static constexpr int WV_OFF  = 155648;   // K=256 N=256
static constexpr int WO_OFF  = 221184;   // K=256 N=256
static constexpr int WM1_OFF = 286720;   // K=256 N=256
static constexpr int WM2_OFF = 352256;   // K=256 N=64
static constexpr int WL1_OFF = 368640;   // K=256 N=256
static constexpr int WL2_OFF = 434176;   // K=256 N=64

// LDS byte offsets (dynamic shared, 160 KiB total), heavily time-shared
static constexpr int XOFF   = 0;        // X  [2][64][256] bf16 swz, stride 512 (64K), ph1->ph4
static constexpr int WLOFF  = 0;        // softmax w [2][4][8][64] stride 128 (8K), ph4->ph5
static constexpr int ATOFF  = 8192;     // attn [16][256] stride 512 (8K), ph6->ph7
static constexpr int HOFF   = 16384;    // hidden [16][256] (8K), ph7->ph8
static constexpr int M1OFF  = 24576;    // m1 [16][256] (8K)
static constexpr int L1OFF  = 32768;    // l1 [16][256] (8K)
static constexpr int XTOFF  = 65536;    // XT [2][256][64] stride 128 (64K), ph1->ph5
static constexpr int EOFF   = 131072;   // E [2][64][96] stride 192 (24K), ph0->ph1
static constexpr int TOFF   = 131072;   // t [4][16][256] stride 512 (32K), ph3->ph4
static constexpr int WXOFF  = 131072;   // wXp [16][1024] stride 2048 (32K), ph5->ph6
static constexpr int ACTOFF = 155648;   // 16 ints (inside q region, dead before q written)
static constexpr int QOFF   = 155648;   // q [16][256] stride 512 (8K), ph2->ph3
static constexpr int LDS_BYTES = 163840;

DEVINL unsigned short f2bf(float f) {
  union { float f; unsigned u; } x; x.f = f;
  unsigned r = x.u + 0x7fffu + ((x.u >> 16) & 1u);
  return (unsigned short)(r >> 16);
}

DEVINL f32x4 mfma(short8 a, short8 b, f32x4 c) {
  return __builtin_amdgcn_mfma_f32_16x16x32_bf16(a, b, c, 0, 0, 0);
}

DEVINL short8 ldfrag(const unsigned short* wf, int off, int nt, int kt, int nkt, int lane) {
  return *(const short8*)(wf + off + ((nt * nkt + kt) << 9) + (lane << 3));
}

// ---------- prep: fp32 weights -> bf16 MFMA B-fragments (coalesced loads) ----------
__global__ __launch_bounds__(512) void prep_kernel(
    const float* We, const float* Win, const float* Wout, const float* Wm1,
    const float* Wm2, const float* Wl1, const float* Wl2, unsigned short* wf) {
  const int m = blockIdx.y;
  const int idx = blockIdx.x * 512 + threadIdx.x;
  if (m == 2) {  // WKT: per-head Wk^T. elem: Win[d*768 + 256 + h*64 + hd]
    if (idx >= 65536) return;
    const int h = idx >> 14, d = (idx >> 6) & 255, hd = idx & 63;
    const float v = Win[(long)d * 768 + 256 + h * 64 + hd];
    const int kt = hd >> 5, gg = (hd >> 3) & 3, j = hd & 7;
    wf[WKT_OFF + (((h * 16 + (d >> 4)) * 2 + kt) << 9) + (gg * 16 + (d & 15)) * 8 + j] =
        f2bf(v);
    return;
  }
  const int Ks[9]  = {96, 256, 0, 256, 256, 256, 256, 256, 256};
  const int Ns[9]  = {256, 256, 0, 256, 256, 256, 64, 256, 64};
  const int ld_[9] = {256, 768, 0, 768, 256, 256, 64, 256, 64};
  const int co_[9] = {0, 0, 0, 512, 0, 0, 0, 0, 0};
  const int off[9] = {WE_OFF, WQ_OFF, 0, WV_OFF, WO_OFF, WM1_OFF, WM2_OFF, WL1_OFF, WL2_OFF};
  const float* S[9] = {We, Win, Win, Win, Wout, Wm1, Wm2, Wl1, Wl2};
  const int K = Ks[m], N = Ns[m];
  if (idx >= K * N) return;
  const int row = idx / N, col = idx - row * N;
  const float v = S[m][(long)row * ld_[m] + co_[m] + col];
  const int nkt = K >> 5;
  wf[off[m] + ((((col >> 4) * nkt) + (row >> 5)) << 9) +
     ((((row >> 3) & 3) << 4) + (col & 15)) * 8 + (row & 7)] = f2bf(v);
}

// ---------- fused main kernel: 1024 threads (16 waves), 2 batch items ----------
__global__ __launch_bounds__(1024, 4) void fused_kernel(
    const float* __restrict__ entities, const int* __restrict__ entity_mask,
    const int* __restrict__ obs_mask, const float* __restrict__ acts,
    const float* __restrict__ Wa, const float* __restrict__ be,
    const float* __restrict__ bout, const float* __restrict__ bm1,
    const float* __restrict__ bm2, const float* __restrict__ bl1,
    const float* __restrict__ bl2, const unsigned short* __restrict__ wf,
    float* __restrict__ out) {
  extern __shared__ char sm[];
  const int tid = threadIdx.x;
  const int w = tid >> 6, lane = tid & 63;
  const int g = lane >> 4, c = lane & 15;
  const int ig0 = blockIdx.x * 2;

  // ---- ph0: entities -> E (bf16, swz), action ids
  {
    const int it = tid >> 9, i = tid & 511;
    const int row = i >> 3, seg = i & 7;
    const float* src = entities + (long)(ig0 + it) * 6144 + row * 96 + seg * 12;
    const int ebase = EOFF + it * 12288 + row * 192;
    const int sw = (row & 3) << 4;
#pragma unroll
    for (int p = 0; p < 3; ++p) {
      float4 f = *(const float4*)(src + p * 4);
      uint2v u;
      u.x = f2bf(f.x) | ((unsigned)f2bf(f.y) << 16);
      u.y = f2bf(f.z) | ((unsigned)f2bf(f.w) << 16);
      *(uint2v*)(sm + ebase + ((seg * 24 + p * 8) ^ sw)) = u;
    }
    if (tid < 16) {
      const float* oh = acts + ((long)(ig0 + (tid >> 3)) * 8 + (tid & 7)) * 16;
      int id = 0;
#pragma unroll
      for (int a = 0; a < 16; ++a) if (oh[a] > 0.5f) id = a;
      ((int*)(sm + ACTOFF))[tid] = id;
    }
  }
  __syncthreads();

  // ---- ph1: x = relu(E@We + ha + be) -> X and XT (packed b64)
  {
    f32x4 acc[2][4] = {};
#pragma unroll
    for (int kt = 0; kt < 3; ++kt) {
      short8 b = ldfrag(wf, WE_OFF, w, kt, 3, lane);
#pragma unroll
      for (int it = 0; it < 2; ++it)
#pragma unroll
        for (int mt = 0; mt < 4; ++mt) {
          const int row = mt * 16 + c;
          short8 a = *(const short8*)(sm + EOFF + it * 12288 + row * 192 +
                                      ((kt * 64 + g * 16) ^ ((row & 3) << 4)));
          acc[it][mt] = mfma(a, b, acc[it][mt]);
        }
    }
    const int col = w * 16 + c;
    const float bev = be[col];
#pragma unroll
    for (int it = 0; it < 2; ++it)
#pragma unroll
      for (int mt = 0; mt < 4; ++mt) {
        float vv[4];
#pragma unroll
        for (int r = 0; r < 4; ++r) {
          const int row = mt * 16 + g * 4 + r;
          float v = acc[it][mt][r] + bev;
          if (row < 8) {
            int id = ((const int*)(sm + ACTOFF))[it * 8 + row];
            v += Wa[id * 256 + col];
          }
          v = fmaxf(v, 0.f);
          vv[r] = v;
          *(unsigned short*)(sm + XOFF + it * 32768 + row * 512 +
                             ((col * 2) ^ ((row & 7) << 4))) = f2bf(v);
        }
        uint2v u;
        u.x = f2bf(vv[0]) | ((unsigned)f2bf(vv[1]) << 16);
        u.y = f2bf(vv[2]) | ((unsigned)f2bf(vv[3]) << 16);
        *(uint2v*)(sm + XTOFF + it * 32768 + col * 128 +
                   ((mt * 32 + g * 8) ^ ((col & 7) << 4))) = u;
      }
  }
  __syncthreads();

  // ---- ph2: q (items packed into 16 rows) = x[0:8]@Wq -> q
  {
    f32x4 qa = {0.f, 0.f, 0.f, 0.f};
#pragma unroll
    for (int kt = 0; kt < 8; ++kt) {
      short8 b = ldfrag(wf, WQ_OFF, w, kt, 8, lane);
      short8 a = *(const short8*)(sm + XOFF + (c >> 3) * 32768 + (c & 7) * 512 +
                                  ((kt * 64 + g * 16) ^ ((c & 7) << 4)));
      qa = mfma(a, b, qa);
    }
#pragma unroll
    for (int r = 0; r < 4; ++r) {
      const int qq = g * 4 + r;
      *(unsigned short*)(sm + QOFF + qq * 512 +
                         (((w * 16 + c) * 2) ^ ((qq & 7) << 4))) = f2bf(qa[r]);
    }
  }
  __syncthreads();

  // ---- ph3: t[h] = q_hslice @ Wk^T[h]  (-> t, overlays q after in-phase barrier)
  {
    const int h = w >> 2, dq = w & 3;
    f32x4 ta[4] = {};
#pragma unroll
    for (int kt = 0; kt < 2; ++kt) {
      short8 a = *(const short8*)(sm + QOFF + c * 512 +
                                  ((h * 128 + kt * 64 + g * 16) ^ ((c & 7) << 4)));
#pragma unroll
      for (int n = 0; n < 4; ++n) {
        short8 b = ldfrag(wf, WKT_OFF, h * 16 + dq * 4 + n, kt, 2, lane);
        ta[n] = mfma(a, b, ta[n]);
      }
    }
    __syncthreads();  // all q reads done before t overwrites the region
#pragma unroll
    for (int n = 0; n < 4; ++n)
#pragma unroll
      for (int r = 0; r < 4; ++r) {
        const int qq = g * 4 + r;
        const int col = (dq * 4 + n) * 16 + c;
        *(unsigned short*)(sm + TOFF + h * 8192 + qq * 512 +
                           ((col * 2) ^ ((qq & 7) << 4))) = f2bf(ta[n][r]);
      }
  }
  __syncthreads();

  // ---- ph4: logits = t @ x^T, mask, softmax -> w_lds (8 active waves)
  {
    const int it = (w >> 2) & 1, h = w & 3;
    float wvals[4][4];
    f32x4 lac[4] = {};
    if (w < 8) {
#pragma unroll
      for (int kt = 0; kt < 8; ++kt) {
        short8 a = *(const short8*)(sm + TOFF + h * 8192 + (it * 8 + (c & 7)) * 512 +
                                    ((kt * 64 + g * 16) ^ ((c & 7) << 4)));
#pragma unroll
        for (int nt = 0; nt < 4; ++nt) {
          const int key = nt * 16 + c;
          short8 b = *(const short8*)(sm + XOFF + it * 32768 + key * 512 +
                                      ((kt * 64 + g * 16) ^ ((key & 7) << 4)));
          lac[nt] = mfma(a, b, lac[nt]);
        }
      }
      if (g < 2) {
        const int* obs = obs_mask + (long)(ig0 + it) * 4096;
#pragma unroll
        for (int r = 0; r < 4; ++r) {
          const int qi = g * 4 + r;
          float vals[4];
#pragma unroll
          for (int nt = 0; nt < 4; ++nt) {
            int msk = obs[qi * 64 + nt * 16 + c];
            vals[nt] = msk ? -INFINITY : lac[nt][r] * 0.125f;
          }
          float mx = fmaxf(fmaxf(vals[0], vals[1]), fmaxf(vals[2], vals[3]));
#pragma unroll
          for (int d = 1; d < 16; d <<= 1) mx = fmaxf(mx, __shfl_xor(mx, d, 64));
          float s = 0.f;
#pragma unroll
          for (int nt = 0; nt < 4; ++nt) {
            float e = (mx == -INFINITY) ? 0.f : expf(vals[nt] - mx);
            vals[nt] = e; s += e;
          }
#pragma unroll
          for (int d = 1; d < 16; d <<= 1) s += __shfl_xor(s, d, 64);
          const float inv = (s > 0.f) ? 1.f / s : 0.f;
#pragma unroll
          for (int nt = 0; nt < 4; ++nt) wvals[r][nt] = vals[nt] * inv;
        }
      }
    }
    __syncthreads();  // x dead; w_lds overlays X region
    if (w < 8 && g < 2) {
#pragma unroll
      for (int r = 0; r < 4; ++r) {
        const int qi = g * 4 + r;
#pragma unroll
        for (int nt = 0; nt < 4; ++nt) {
          const int key = nt * 16 + c;
          *(unsigned short*)(sm + WLOFF + ((it * 4 + h) * 8 + qi) * 128 +
                             ((key * 2) ^ ((qi & 7) << 4))) = f2bf(wvals[r][nt]);
        }
      }
    }
  }
  __syncthreads();

  // ---- ph5: wX[h] = w[h] @ x  (B from XT) -> wXp [16][1024] (overlays t)
  {
    const int it = w >> 3, h = (w >> 1) & 3, dh = w & 1;
    f32x4 xa[8] = {};
#pragma unroll
    for (int kt = 0; kt < 2; ++kt) {
      short8 a = *(const short8*)(sm + WLOFF + ((it * 4 + h) * 8 + (c & 7)) * 128 +
                                  ((kt * 64 + g * 16) ^ ((c & 7) << 4)));
#pragma unroll
      for (int n = 0; n < 8; ++n) {
        const int d = dh * 128 + n * 16 + c;
        short8 b = *(const short8*)(sm + XTOFF + it * 32768 + d * 128 +
                                    ((kt * 64 + g * 16) ^ ((d & 7) << 4)));
        xa[n] = mfma(a, b, xa[n]);
      }
    }
    if (g < 2) {
#pragma unroll
      for (int n = 0; n < 8; ++n)
#pragma unroll
        for (int r = 0; r < 4; ++r) {
          const int qq = it * 8 + g * 4 + r;
          const int col = h * 256 + dh * 128 + n * 16 + c;
          *(unsigned short*)(sm + WXOFF + qq * 2048 +
                             ((col * 2) ^ ((qq & 7) << 4))) = f2bf(xa[n][r]);
        }
    }
  }
  __syncthreads();

  // ---- ph6: attn = wXp @ Wv (per head, items packed) -> attnL
  {
    const int h = w >> 2, n = w & 3;
    f32x4 aac = {0.f, 0.f, 0.f, 0.f};
#pragma unroll
    for (int kt = 0; kt < 8; ++kt) {
      short8 a = *(const short8*)(sm + WXOFF + c * 2048 +
                                  ((h * 512 + kt * 64 + g * 16) ^ ((c & 7) << 4)));
      short8 b = ldfrag(wf, WV_OFF, h * 4 + n, kt, 8, lane);
      aac = mfma(a, b, aac);
    }
#pragma unroll
    for (int r = 0; r < 4; ++r) {
      const int qq = g * 4 + r;
      const int col = (h * 4 + n) * 16 + c;
      *(unsigned short*)(sm + ATOFF + qq * 512 +
                         ((col * 2) ^ ((qq & 7) << 4))) = f2bf(aac[r]);
    }
  }
  __syncthreads();

  // ---- ph7: hidden = mask/relu(attnL @ Wout + bout)
  {
    f32x4 hc = {0.f, 0.f, 0.f, 0.f};
#pragma unroll
    for (int kt = 0; kt < 8; ++kt) {
      short8 a = *(const short8*)(sm + ATOFF + c * 512 +
                                  ((kt * 64 + g * 16) ^ ((c & 7) << 4)));
      short8 b = ldfrag(wf, WO_OFF, w, kt, 8, lane);
      hc = mfma(a, b, hc);
    }
    const int col = w * 16 + c;
    const float bo = bout[col];
#pragma unroll
    for (int r = 0; r < 4; ++r) {
      const int qq = g * 4 + r;
      const int em = entity_mask[(long)(ig0 + (qq >> 3)) * 64 + (qq & 7)];
      float v = hc[r] + bo;
      v = em ? 0.f : fmaxf(v, 0.f);
      *(unsigned short*)(sm + HOFF + qq * 512 + ((col * 2) ^ ((qq & 7) << 4))) = f2bf(v);
    }
  }
  __syncthreads();

  // ---- ph8: m1 = relu(hidden@Wm1+bm1), l1 = relu(hidden@Wl1+bl1)
  {
    const int which = w >> 3, np = w & 7;
    const int woff = which ? WL1_OFF : WM1_OFF;
    const float* bias = which ? bl1 : bm1;
    const int base = which ? L1OFF : M1OFF;
    f32x4 mc[2] = {};
#pragma unroll
    for (int kt = 0; kt < 8; ++kt) {
      short8 a = *(const short8*)(sm + HOFF + c * 512 +
                                  ((kt * 64 + g * 16) ^ ((c & 7) << 4)));
      short8 b0 = ldfrag(wf, woff, np * 2, kt, 8, lane);
      short8 b1 = ldfrag(wf, woff, np * 2 + 1, kt, 8, lane);
      mc[0] = mfma(a, b0, mc[0]);
      mc[1] = mfma(a, b1, mc[1]);
    }
#pragma unroll
    for (int n = 0; n < 2; ++n) {
      const int col = (np * 2 + n) * 16 + c;
      const float bv = bias[col];
#pragma unroll
      for (int r = 0; r < 4; ++r) {
        const int qq = g * 4 + r;
        float v = fmaxf(mc[n][r] + bv, 0.f);
        *(unsigned short*)(sm + base + qq * 512 + ((col * 2) ^ ((qq & 7) << 4))) = f2bf(v);
      }
    }
  }
  __syncthreads();

  // ---- ph9: mean = m1@Wm2+bm2 ; logvar = clip(l1@Wl2+bl2) -> out
  if (w < 8) {
    const int which = w >> 2, nt = w & 3;
    const int woff = which ? WL2_OFF : WM2_OFF;
    const int base = which ? L1OFF : M1OFF;
    const float* bias = which ? bl2 : bm2;
    f32x4 oc = {0.f, 0.f, 0.f, 0.f};
#pragma unroll
    for (int kt = 0; kt < 8; ++kt) {
      short8 a = *(const short8*)(sm + base + c * 512 +
                                  ((kt * 64 + g * 16) ^ ((c & 7) << 4)));
      short8 b = ldfrag(wf, woff, nt, kt, 8, lane);
      oc = mfma(a, b, oc);
    }
    const float bv = bias[nt * 16 + c];
#pragma unroll
    for (int r = 0; r < 4; ++r) {
      const int qq = g * 4 + r;
      float v = oc[r] + bv;
      if (which) v = fminf(fmaxf(v, -10.f), 0.f);
      out[(long)which * 2097152 + (long)(ig0 + (qq >> 3)) * 512 + (qq & 7) * 64 +
          nt * 16 + c] = v;
    }
  }
}

extern "C" void kernel_launch(void* const* d_in, const int* in_sizes, int n_in,
                              void* d_out, int out_size, void* d_ws, size_t ws_size,
                              hipStream_t stream) {
  const float* entities    = (const float*)d_in[0];
  const int*   entity_mask = (const int*)d_in[1];
  const int*   obs_mask    = (const int*)d_in[2];
  const float* acts        = (const float*)d_in[3];
  const float* We   = (const float*)d_in[4];
  const float* be   = (const float*)d_in[5];
  const float* Wa   = (const float*)d_in[6];
  const float* Win  = (const float*)d_in[7];
  const float* Wout = (const float*)d_in[8];
  const float* bout = (const float*)d_in[9];
  const float* Wm1  = (const float*)d_in[10];
  const float* bm1  = (const float*)d_in[11];
  const float* Wm2  = (const float*)d_in[12];
  const float* bm2  = (const float*)d_in[13];
  const float* Wl1  = (const float*)d_in[14];
  const float* bl1  = (const float*)d_in[15];
  const float* Wl2  = (const float*)d_in[16];
  const float* bl2  = (const float*)d_in[17];
  unsigned short* wf = (unsigned short*)d_ws;

  prep_kernel<<<dim3(128, 9), 512, 0, stream>>>(We, Win, Wout, Wm1, Wm2, Wl1, Wl2, wf);

  hipFuncSetAttribute((const void*)fused_kernel,
                      hipFuncAttributeMaxDynamicSharedMemorySize, LDS_BYTES);
  fused_kernel<<<NBLK, 1024, LDS_BYTES, stream>>>(
      entities, entity_mask, obs_mask, acts, Wa, be, bout, bm1, bm2, bl1, bl2,
      wf, (float*)d_out);
}